// Round 6
// baseline (1294.670 us; speedup 1.0000x reference)
//
#include <hip/hip_runtime.h>
#include <math.h>

// ---- model constants ----
#define BS_TOT   1024          // B*S
#define DM       256           // d_model
#define DST      128           // d_state
#define TSTEPS   8
#define DECAYF   0.6065306597126334f
#define SCALEF   0.17677669529663689f   // 1/sqrt(32)
#define NE       (BS_TOT * DM)          // 262144

#define GLOAD_LDS16(g, l) \
    __builtin_amdgcn_global_load_lds( \
        (const __attribute__((address_space(1))) void*)(g), \
        (__attribute__((address_space(3))) void*)(l), 16, 0, 0)

// ======================= embedding =======================
__global__ void embed_k(const int* __restrict__ ids, const float* __restrict__ emb,
                        float* __restrict__ tok) {
    int r = blockIdx.x, c = threadIdx.x;
    tok[r * DM + c] = emb[(size_t)ids[r] * DM + c];
}

// ======================= per-layer prep: zero state + transpose weights ==========
// grid 1024 x 256 (262144 threads)
__global__ void prep_k(float* __restrict__ h, float* __restrict__ sv, float* __restrict__ ov,
                       float* __restrict__ W1T, float* __restrict__ WoT, float* __restrict__ CT,
                       const float* __restrict__ Al, const float* __restrict__ Wql,
                       const float* __restrict__ Wol, const float* __restrict__ Cl,
                       int* __restrict__ cnts) {
    int i = blockIdx.x * 256 + threadIdx.x;
    if (i < BS_TOT * DST) { h[i] = 0.f; sv[i] = 0.f; }
    ov[i] = 0.f;
    if (i < 32768) {
        int k = i >> 8, n = i & 255;
        W1T[i] = (n < 128) ? Al[n * 128 + k] : Wql[(n - 128) * 128 + k];
        CT[i]  = Cl[n * 128 + k];
    }
    if (i < 16384) {
        int k = i >> 7, n = i & 127;
        WoT[i] = Wol[n * 128 + k];
    }
    if (i < 16) cnts[i] = 0;
}

// ======================= k-half transpose: kv[key][0..127] -> kT[d][key] =========
__global__ __launch_bounds__(256) void ktrans_k(const float* __restrict__ kv,
                                                float* __restrict__ kT) {
    __shared__ float tile[64][133];
    const float* src = kv + (size_t)blockIdx.y * NE;
    float* dst = kT + (size_t)blockIdx.y * (128 * 1024);
    const int kc = blockIdx.x, tid = threadIdx.x;
#pragma unroll
    for (int i = 0; i < 32; ++i) {
        int idx = i * 256 + tid;
        int key = idx >> 7, d = idx & 127;
        tile[key][d] = src[(size_t)(kc * 64 + key) * 256 + d];
    }
    __syncthreads();
#pragma unroll
    for (int i = 0; i < 32; ++i) {
        int idx = i * 256 + tid;
        int d = idx >> 6, key = idx & 63;
        dst[(size_t)d * 1024 + kc * 64 + key] = tile[key][d];
    }
}

// ======================= time-mean =======================
__global__ void mean_k(const float* __restrict__ outs, float* __restrict__ ti) {
    int i = blockIdx.x * 256 + threadIdx.x;
    float s = 0.f;
#pragma unroll
    for (int t = 0; t < TSTEPS; ++t) s += outs[t * NE + i];
    ti[i] = s * 0.125f;
}

// ======================= generic fp32 GEMM (plain, +bias) =======================
template <int BM, int BN, int BK, int TM, int TN>
__global__ __launch_bounds__((BM / TM) * (BN / TN))
void gemm_k(const float* __restrict__ Amat, const float* __restrict__ Wmat,
            const float* __restrict__ bias, float* __restrict__ outp,
            int M, int N, int K) {
    constexpr int NT  = (BM / TM) * (BN / TN);
    constexpr int NXT = BN / TN;
    __shared__ float As[BK][BM + 4];
    __shared__ float Bs[BK][BN + 4];
    const int tid = threadIdx.x;
    const int n0 = blockIdx.x * BN, m0 = blockIdx.y * BM;
    const int tx = tid % NXT, ty = tid / NXT;
    float acc[TM][TN] = {};

    for (int k0 = 0; k0 < K; k0 += BK) {
#pragma unroll
        for (int i = 0; i < (BM * BK) / NT; ++i) {
            int idx = i * NT + tid;
            int kk = idx % BK, mm = idx / BK;
            As[kk][mm] = Amat[(size_t)(m0 + mm) * K + k0 + kk];
        }
#pragma unroll
        for (int i = 0; i < (BN * BK) / NT; ++i) {
            int idx = i * NT + tid;
            int kk = idx % BK, nn = idx / BK;
            Bs[kk][nn] = Wmat[(size_t)(n0 + nn) * K + k0 + kk];
        }
        __syncthreads();
#pragma unroll
        for (int kk = 0; kk < BK; ++kk) {
            float a[TM], b[TN];
#pragma unroll
            for (int i = 0; i < TM; ++i) a[i] = As[kk][ty * TM + i];
#pragma unroll
            for (int j = 0; j < TN; ++j) b[j] = Bs[kk][tx * TN + j];
#pragma unroll
            for (int i = 0; i < TM; ++i)
#pragma unroll
                for (int j = 0; j < TN; ++j) acc[i][j] += a[i] * b[j];
        }
        __syncthreads();
    }
#pragma unroll
    for (int i = 0; i < TM; ++i) {
        int mr = m0 + ty * TM + i;
#pragma unroll
        for (int j = 0; j < TN; ++j) {
            int nc = n0 + tx * TN + j;
            float x = acc[i][j];
            if (bias) x += bias[nc];
            outp[(size_t)mr * N + nc] = x;
        }
    }
}

// ======================= logits GEMM: 128x128x32, global_load_lds + XOR swizzle ===
// 2000 blocks x 256 thr, XCD-swizzled. LDS-pipe-bound kernel: removing the
// reg-staged ds_write side (~1170 LDS-cyc/k0 incl. 4-way conflicts) via DMA
// staging. As2/Bs2 are row-major [row][32] (LINEAR dest, required by
// global_load_lds); read bank conflicts fixed by both-sides XOR swizzle:
// stored k-group = k4 ^ ((row>>2)&7) applied on the GLOBAL source address,
// reads use the same involution. FMA order (k0 asc, kk asc) -> bit-identical.
__global__ __launch_bounds__(256) void gemm_out_k(
    const float* __restrict__ Amat, const float* __restrict__ Wmat,
    const float* __restrict__ bias, float* __restrict__ outp)
{
    constexpr int K = 256, N = 32000;
    __shared__ float As2[128 * 32];   // 16 KB, [mm][kk] swizzled k4-groups
    __shared__ float Bs2[128 * 32];   // 16 KB, [nn][kk]
    const int tid = threadIdx.x;

    // bijective XCD swizzle: 2000 blocks, 2000 % 8 == 0
    const int bid = blockIdx.x;
    const int g   = (bid & 7) * 250 + (bid >> 3);
    const int m0  = (g & 7) * 128;
    const int n0  = (g >> 3) * 128;

    const int tx = tid & 15, ty = tid >> 4;
    float acc[8][8] = {};

    const int swa = ty & 7;           // (row>>2)&7 for rows ty*4+i and 64+ty*4+i
    const int swb = tx & 7;

    for (int k0 = 0; k0 < K; k0 += 32) {
        // stage: idx = i*256+tid -> row = idx>>3, k4 = idx&7; dest linear idx*16B.
        // source k-group pre-swizzled so phys slot k4 holds logical k4^swz(row).
#pragma unroll
        for (int i = 0; i < 4; ++i) {
            int idx = i * 256 + tid;
            int row = idx >> 3, k4 = idx & 7;
            int k4s = k4 ^ ((row >> 2) & 7);
            GLOAD_LDS16(&Amat[(size_t)(m0 + row) * K + k0 + k4s * 4], &As2[idx * 4]);
            GLOAD_LDS16(&Wmat[(size_t)(n0 + row) * K + k0 + k4s * 4], &Bs2[idx * 4]);
        }
        __syncthreads();   // compiler drains vmcnt(0) before s_barrier

#pragma unroll
        for (int kg = 0; kg < 8; ++kg) {
            const int pa = (kg ^ swa) * 4;   // physical slot of logical group kg
            const int pb = (kg ^ swb) * 4;
            float4 a0[4], a1[4], b0[4], b1[4];
#pragma unroll
            for (int i = 0; i < 4; ++i) {
                a0[i] = *(const float4*)&As2[(ty * 4 + i) * 32 + pa];
                a1[i] = *(const float4*)&As2[(64 + ty * 4 + i) * 32 + pa];
                b0[i] = *(const float4*)&Bs2[(tx * 4 + i) * 32 + pb];
                b1[i] = *(const float4*)&Bs2[(64 + tx * 4 + i) * 32 + pb];
            }
#pragma unroll
            for (int kk2 = 0; kk2 < 4; ++kk2) {   // logical kk = kg*4 + kk2, asc
                float a[8], b[8];
#pragma unroll
                for (int i = 0; i < 4; ++i) {
                    a[i]     = ((const float*)&a0[i])[kk2];
                    a[4 + i] = ((const float*)&a1[i])[kk2];
                    b[i]     = ((const float*)&b0[i])[kk2];
                    b[4 + i] = ((const float*)&b1[i])[kk2];
                }
#pragma unroll
                for (int i = 0; i < 8; ++i)
#pragma unroll
                    for (int j = 0; j < 8; ++j) acc[i][j] += a[i] * b[j];
            }
        }
        __syncthreads();
    }

    float bv[8];
    *(float4*)&bv[0] = *(const float4*)&bias[n0 + tx * 4];
    *(float4*)&bv[4] = *(const float4*)&bias[n0 + 64 + tx * 4];
#pragma unroll
    for (int i = 0; i < 8; ++i) {
        const int mr = m0 + ((i < 4) ? (ty * 4 + i) : (64 + ty * 4 + i - 4));
        float4 o0, o1;
        o0.x = acc[i][0] + bv[0]; o0.y = acc[i][1] + bv[1];
        o0.z = acc[i][2] + bv[2]; o0.w = acc[i][3] + bv[3];
        o1.x = acc[i][4] + bv[4]; o1.y = acc[i][5] + bv[5];
        o1.z = acc[i][6] + bv[6]; o1.w = acc[i][7] + bv[7];
        float* dst = &outp[(size_t)mr * N + n0];
        *(float4*)(dst + tx * 4)      = o0;
        *(float4*)(dst + 64 + tx * 4) = o1;
    }
}

// ======================= L-kernel: LIF of step t-1 + q of step t ==================
// grid 256 blocks x 256 thr, 4 rows per block. EXACT round-0 version (separate
// A2 and B1 walks): the fused/prefetch variant measured +15 us across rounds.
__global__ __launch_bounds__(256) void lif_k(
    const float* __restrict__ W1T,        // [128][256]  ([A|Wq] transposed)
    const float* __restrict__ WoT,        // [128][128]
    const float* __restrict__ CT,         // [128][256]
    const float* __restrict__ bq_w,       // [128]
    const float* __restrict__ bo_w,       // [128]
    float* __restrict__ h,                // [1024][128] spikes (in/out, in-place)
    float* __restrict__ sv,               // [1024][128]
    float* __restrict__ ov,               // [1024][256]
    const float* __restrict__ att_in,     // [1024][128]  att(t-1)
    float* __restrict__ outs_prev,        // outs[t-1]
    float* __restrict__ q_g,              // [1024][128]
    int* __restrict__ cnt1, int* __restrict__ cnt2, int t, int do_B)
{
    __shared__ float hA_s[4 * 128];
    __shared__ float h2_s[4 * 128];
    __shared__ float att_s[4 * 128];
    __shared__ unsigned long long umr_s[4][2];
    __shared__ unsigned long long um_s[2];
    __shared__ float thr_s[2];

    const int tid = threadIdx.x;
    const int r0 = blockIdx.x * 4;

    if (tid == 0) {
        float ts = 1.0f, to = 1.0f;
        for (int i = 0; i < t - 1; ++i) {
            float e1 = (float)cnt1[i] * (1.f / 131072.f) - 0.02f;
            ts = fmaxf(ts + 0.1f * e1, 0.5f);
            float e2 = (float)cnt2[i] * (1.f / 262144.f) - 0.02f;
            to = fmaxf(to + 0.1f * e2, 0.5f);
        }
        thr_s[0] = ts; thr_s[1] = to;
    }
    hA_s[tid]       = h[r0 * 128 + tid];
    hA_s[256 + tid] = h[r0 * 128 + 256 + tid];
    if (t > 0) {
        att_s[tid]       = att_in[r0 * 128 + tid];
        att_s[256 + tid] = att_in[r0 * 128 + 256 + tid];
    }
    __syncthreads();
    {   // per-row ballots of h_old (wave w -> row w)
        int w = tid >> 6, l = tid & 63;
        unsigned long long b0 = __ballot(hA_s[w * 128 + l] != 0.f);
        unsigned long long b1 = __ballot(hA_s[w * 128 + 64 + l] != 0.f);
        if (l == 0) { umr_s[w][0] = b0; umr_s[w][1] = b1; }
    }
    __syncthreads();
    if (tid == 0) {
        um_s[0] = umr_s[0][0] | umr_s[1][0] | umr_s[2][0] | umr_s[3][0];
        um_s[1] = umr_s[0][1] | umr_s[1][1] | umr_s[2][1] | umr_s[3][1];
    }
    __syncthreads();

    const int n = tid & 127, half = tid >> 7;   // rows 2*half, 2*half+1
    const int ra = half * 2, rb = half * 2 + 1;

    if (t > 0) {
        // ---- A1: st = h_old@A^T (sparse), b = att@Wo^T (dense); LIF1 -> h2 ----
        float sta = 0.f, stb = 0.f;
        unsigned long long u = um_s[0];
        while (u) {
            int k = __builtin_ctzll(u); u &= u - 1;
            float w = W1T[(k << 8) + n];
            sta += hA_s[ra * 128 + k] * w; stb += hA_s[rb * 128 + k] * w;
        }
        u = um_s[1];
        while (u) {
            int kk = __builtin_ctzll(u); u &= u - 1;
            int k = 64 + kk;
            float w = W1T[(k << 8) + n];
            sta += hA_s[ra * 128 + k] * w; stb += hA_s[rb * 128 + k] * w;
        }
        float ba = 0.f, bb = 0.f;
        for (int i4 = 0; i4 < 32; ++i4) {
            const int i = i4 * 4;
            float w0 = WoT[(i + 0) * 128 + n];
            float w1 = WoT[(i + 1) * 128 + n];
            float w2 = WoT[(i + 2) * 128 + n];
            float w3 = WoT[(i + 3) * 128 + n];
            float4 aa = *(const float4*)&att_s[ra * 128 + i];
            float4 ab = *(const float4*)&att_s[rb * 128 + i];
            ba += aa.x * w0; ba += aa.y * w1; ba += aa.z * w2; ba += aa.w * w3;
            bb += ab.x * w0; bb += ab.y * w1; bb += ab.z * w2; bb += ab.w * w3;
        }
        float ts = thr_s[0];
        float xa = ba + bo_w[n]; xa += sta;
        float va = sv[(r0 + ra) * 128 + n];
        float vpa = va * DECAYF + xa;
        float spa = (vpa - ts >= 0.f) ? 1.f : 0.f;
        h[(r0 + ra) * 128 + n]  = spa;
        sv[(r0 + ra) * 128 + n] = vpa * (1.f - spa);
        h2_s[ra * 128 + n] = spa;

        float xb = bb + bo_w[n]; xb += stb;
        float vb = sv[(r0 + rb) * 128 + n];
        float vpb = vb * DECAYF + xb;
        float spb = (vpb - ts >= 0.f) ? 1.f : 0.f;
        h[(r0 + rb) * 128 + n]  = spb;
        sv[(r0 + rb) * 128 + n] = vpb * (1.f - spb);
        h2_s[rb * 128 + n] = spb;

        unsigned long long bba = __ballot(spa != 0.f);
        unsigned long long bbb = __ballot(spb != 0.f);
        int w = tid >> 6, l = tid & 63;
        if (l == 0) {
            umr_s[ra][w & 1] = bba;
            umr_s[rb][w & 1] = bbb;
            atomicAdd(&cnt1[t - 1], __popcll(bba) + __popcll(bbb));
        }
    } else {
        h2_s[tid]       = hA_s[tid];          // zeros
        h2_s[256 + tid] = hA_s[256 + tid];
        // umr stays = zero ballots of h
    }
    __syncthreads();
    if (tid == 0) {
        um_s[0] = umr_s[0][0] | umr_s[1][0] | umr_s[2][0] | umr_s[3][0];
        um_s[1] = umr_s[0][1] | umr_s[1][1] | umr_s[2][1] | umr_s[3][1];
    }
    __syncthreads();

    if (t > 0) {
        // ---- A2: out_pot = h2@C^T (sparse) -> LIF2 -> outs[t-1] ----
        const int n2 = tid;
        float a0 = 0.f, a1 = 0.f, a2 = 0.f, a3 = 0.f;
        unsigned long long u = um_s[0];
        while (u) {
            int k = __builtin_ctzll(u); u &= u - 1;
            float w = CT[(k << 8) + n2];
            a0 += h2_s[k] * w;       a1 += h2_s[128 + k] * w;
            a2 += h2_s[256 + k] * w; a3 += h2_s[384 + k] * w;
        }
        u = um_s[1];
        while (u) {
            int kk = __builtin_ctzll(u); u &= u - 1;
            int k = 64 + kk;
            float w = CT[(k << 8) + n2];
            a0 += h2_s[k] * w;       a1 += h2_s[128 + k] * w;
            a2 += h2_s[256 + k] * w; a3 += h2_s[384 + k] * w;
        }
        float to = thr_s[1];
        float accs[4] = {a0, a1, a2, a3};
        float sp[4];
#pragma unroll
        for (int r = 0; r < 4; ++r) {
            float vo = ov[(r0 + r) * 256 + n2];
            float vp = vo * DECAYF + accs[r];
            float s = (vp - to >= 0.f) ? 1.f : 0.f;
            sp[r] = s;
            outs_prev[(size_t)(r0 + r) * 256 + n2] = s;
            ov[(r0 + r) * 256 + n2] = vp * (1.f - s);
        }
        unsigned long long c0 = __ballot(sp[0] != 0.f);
        unsigned long long c1 = __ballot(sp[1] != 0.f);
        unsigned long long c2 = __ballot(sp[2] != 0.f);
        unsigned long long c3 = __ballot(sp[3] != 0.f);
        if ((tid & 63) == 0)
            atomicAdd(&cnt2[t - 1], __popcll(c0) + __popcll(c1) + __popcll(c2) + __popcll(c3));
    }

    if (do_B) {
        // ---- B1: q = h2@Wq^T + bq (sparse), cols 128..255 of W1T ----
        float qa = 0.f, qb = 0.f;
        unsigned long long u = um_s[0];
        while (u) {
            int k = __builtin_ctzll(u); u &= u - 1;
            float w = W1T[(k << 8) + 128 + n];
            qa += h2_s[ra * 128 + k] * w; qb += h2_s[rb * 128 + k] * w;
        }
        u = um_s[1];
        while (u) {
            int kk = __builtin_ctzll(u); u &= u - 1;
            int k = 64 + kk;
            float w = W1T[(k << 8) + 128 + n];
            qa += h2_s[ra * 128 + k] * w; qb += h2_s[rb * 128 + k] * w;
        }
        q_g[(r0 + ra) * 128 + n] = qa + bq_w[n];
        q_g[(r0 + rb) * 128 + n] = qb + bq_w[n];
    }
}

// ======================= S-kernel: scores/softmax/PV for one head =================
// grid = 128 row-tiles x 4 heads = 512 blocks, 256 threads, 8 rows per block.
// Round-0 structure (2-wave PV) + tight v_s[2][64*32] double-buffer (50.3 KB
// total -> still 3 blocks/CU) removing the 2nd barrier per c-iter. Stage writes
// are linear (addr = 4*tid, conflict-free); float2 reads conflict-free at
// stride 32 (banks 2dp..2dp+1 cover all 32). Compute order identical -> bit-exact.
__global__ __launch_bounds__(256) void attn_k(
    const float* __restrict__ q_g,        // [1024][128]
    const float* __restrict__ kT,         // [128][1024]
    const float* __restrict__ kv,         // [1024][256] (v half used)
    float* __restrict__ att_out)          // [1024][128]
{
    __shared__ float p_s[8][1032];
    __shared__ float v_s[2][64 * 32];
    __shared__ float q_s[8][32];
    __shared__ float red_s[8 * 33];
    __shared__ float mrow_s[8], linv_s[8];

    const int tid = threadIdx.x;
    const int hh = blockIdx.x >> 7;
    const int r0 = (blockIdx.x & 127) * 8;

    {   // stage q (8 rows x 32 dims)
        int r = tid >> 5, d = tid & 31;
        q_s[r][d] = q_g[(size_t)(r0 + r) * 128 + hh * 32 + d];
    }
    __syncthreads();

    // ---- B2: scores. Lane owns 4 keys; 2 d-passes continue one ascending chain.
    {
        const int w = tid >> 6, l = tid & 63;
        const int key4 = w * 64 + l;                 // float4 index into 1024 keys
        const float4* kT4 = (const float4*)(kT + (size_t)hh * 32 * 1024);
        float4 acc[8];
#pragma unroll
        for (int pass = 0; pass < 2; ++pass) {
            const int d0 = pass * 16;
            float4 kreg[16];
#pragma unroll
            for (int i = 0; i < 16; ++i) kreg[i] = kT4[(size_t)(d0 + i) * 256 + key4];
#pragma unroll
            for (int r = 0; r < 8; ++r)
                acc[r] = pass ? *(const float4*)&p_s[r][key4 * 4]
                              : make_float4(0.f, 0.f, 0.f, 0.f);
#pragma unroll
            for (int i4 = 0; i4 < 4; ++i4) {
#pragma unroll
                for (int r = 0; r < 8; ++r) {
                    float4 qv = *(const float4*)&q_s[r][d0 + i4 * 4];
                    float4 k0 = kreg[i4 * 4 + 0], k1 = kreg[i4 * 4 + 1];
                    float4 k2 = kreg[i4 * 4 + 2], k3 = kreg[i4 * 4 + 3];
                    acc[r].x += qv.x * k0.x; acc[r].x += qv.y * k1.x;
                    acc[r].x += qv.z * k2.x; acc[r].x += qv.w * k3.x;
                    acc[r].y += qv.x * k0.y; acc[r].y += qv.y * k1.y;
                    acc[r].y += qv.z * k2.y; acc[r].y += qv.w * k3.y;
                    acc[r].z += qv.x * k0.z; acc[r].z += qv.y * k1.z;
                    acc[r].z += qv.z * k2.z; acc[r].z += qv.w * k3.z;
                    acc[r].w += qv.x * k0.w; acc[r].w += qv.y * k1.w;
                    acc[r].w += qv.z * k2.w; acc[r].w += qv.w * k3.w;
                }
            }
            if (pass == 0) {
#pragma unroll
                for (int r = 0; r < 8; ++r)
                    *(float4*)&p_s[r][key4 * 4] = acc[r];
            } else {
#pragma unroll
                for (int r = 0; r < 8; ++r) {
                    acc[r].x *= SCALEF; acc[r].y *= SCALEF;
                    acc[r].z *= SCALEF; acc[r].w *= SCALEF;
                    *(float4*)&p_s[r][key4 * 4] = acc[r];
                }
            }
        }
    }
    __syncthreads();

    // ---- B3: softmax (identical per-row reduction order to earlier rounds) ----
    {
        const int rh = tid >> 5, lg = tid & 31;
        float mx = -1e30f;
        for (int jj = 0; jj < 32; ++jj) mx = fmaxf(mx, p_s[rh][lg + 32 * jj]);
        red_s[rh * 33 + lg] = mx;
        __syncthreads();
        if (tid < 8) {
            float m = red_s[tid * 33];
            for (int j = 1; j < 32; ++j) m = fmaxf(m, red_s[tid * 33 + j]);
            mrow_s[tid] = m;
        }
        __syncthreads();
        float m = mrow_s[rh];
        float ls = 0.f;
        for (int jj = 0; jj < 32; ++jj) {
            int a = lg + 32 * jj;
            float p = expf(p_s[rh][a] - m);
            p_s[rh][a] = p;
            ls += p;
        }
        red_s[rh * 33 + lg] = ls;
        __syncthreads();
        if (tid < 8) {
            float l = 0.f;
            for (int j = 0; j < 32; ++j) l += red_s[tid * 33 + j];
            linv_s[tid] = 1.0f / l;
        }
    }
    __syncthreads();

    // ---- B4: PV. Waves 0,1 compute (4 rows x 16 dim-pairs each); all stage.
    // v_s double-buffered: write(c) -> buf c&1, barrier, compute(c); write(c+1)
    // targets the other buffer and is ordered after barrier(c) in program order,
    // while compute(c-1) on that buffer completed before barrier(c). One barrier
    // per c-iter (16 vs 32).
    {
        const int w = tid >> 6, l = tid & 63;
        const int r = (w & 1) * 4 + (l >> 4);
        const int dp = l & 15;
        const bool act = (w < 2);
        const float4* kv4 = (const float4*)kv;
        float4 stg0, stg1;
        {
            int i0 = tid, i1 = 256 + tid;
            stg0 = kv4[(size_t)(i0 >> 3) * 64 + 32 + hh * 8 + (i0 & 7)];
            stg1 = kv4[(size_t)(i1 >> 3) * 64 + 32 + hh * 8 + (i1 & 7)];
        }
        float a0 = 0.f, a1 = 0.f;
        for (int c = 0; c < 16; ++c) {
            float* vb = v_s[c & 1];
            // (i>>3)*32 + (i&7)*4 == i*4 -> linear, conflict-free, 16B aligned
            *(float4*)&vb[tid * 4]        = stg0;
            *(float4*)&vb[1024 + tid * 4] = stg1;
            if (c < 15) {
                int i0 = tid, i1 = 256 + tid;
                stg0 = kv4[(size_t)((c + 1) * 64 + (i0 >> 3)) * 64 + 32 + hh * 8 + (i0 & 7)];
                stg1 = kv4[(size_t)((c + 1) * 64 + (i1 >> 3)) * 64 + 32 + hh * 8 + (i1 & 7)];
            }
            __syncthreads();
            if (act) {
#pragma unroll 4
                for (int k4 = 0; k4 < 16; ++k4) {
                    const int kb = k4 * 4;
                    float4 p4 = *(const float4*)&p_s[r][c * 64 + kb];
                    float2 v0 = *(const float2*)&vb[(kb + 0) * 32 + 2 * dp];
                    float2 v1 = *(const float2*)&vb[(kb + 1) * 32 + 2 * dp];
                    float2 v2 = *(const float2*)&vb[(kb + 2) * 32 + 2 * dp];
                    float2 v3 = *(const float2*)&vb[(kb + 3) * 32 + 2 * dp];
                    a0 += p4.x * v0.x; a1 += p4.x * v0.y;
                    a0 += p4.y * v1.x; a1 += p4.y * v1.y;
                    a0 += p4.z * v2.x; a1 += p4.z * v2.y;
                    a0 += p4.w * v3.x; a1 += p4.w * v3.y;
                }
            }
        }
        if (act) {
            float li = linv_s[r];
            *(float2*)&att_out[(size_t)(r0 + r) * 128 + hh * 32 + 2 * dp] =
                make_float2(a0 * li, a1 * li);
        }
    }
}

// ======================= host =======================
extern "C" void kernel_launch(void* const* d_in, const int* in_sizes, int n_in,
                              void* d_out, int out_size, void* d_ws, size_t ws_size,
                              hipStream_t stream) {
    (void)in_sizes; (void)n_in; (void)out_size; (void)ws_size;
    const int*   ids  = (const int*)d_in[0];
    const float* emb  = (const float*)d_in[1];
    const float* Aw   = (const float*)d_in[2];
    const float* Cw   = (const float*)d_in[3];
    const float* Wq   = (const float*)d_in[4];
    const float* bq   = (const float*)d_in[5];
    const float* Wkv  = (const float*)d_in[6];
    const float* bkv  = (const float*)d_in[7];
    const float* Wo   = (const float*)d_in[8];
    const float* bo   = (const float*)d_in[9];
    const float* Wout = (const float*)d_in[10];
    const float* bout = (const float*)d_in[11];
    float* out = (float*)d_out;
    float* ws  = (float*)d_ws;

    float* tok  = ws;                       // 262144
    float* bufA = tok  + NE;                // 8*262144
    float* bufB = bufA + 8 * NE;            // 8*262144
    float* kvb  = bufB + 8 * NE;            // 8*262144
    float* kTb  = kvb  + 8 * NE;            // 8*131072
    float* attb = kTb  + 8 * 131072;        // 131072
    float* hbuf = attb + 131072;            // 131072
    float* svb  = hbuf + 131072;            // 131072
    float* ovb  = svb  + 131072;            // 262144
    float* qg   = ovb  + 262144;            // 131072
    float* ti   = qg   + 131072;            // 262144
    float* W1T  = ti   + NE;                // 32768
    float* WoT  = W1T  + 32768;             // 16384
    float* CT   = WoT  + 16384;             // 32768
    int*   cnts = (int*)(CT + 32768);       // cnt1[8], cnt2[8]

    embed_k<<<dim3(1024), dim3(256), 0, stream>>>(ids, emb, tok);

    for (int l = 0; l < 2; ++l) {
        const float* Al   = Aw  + l * 16384;
        const float* Cl   = Cw  + l * 32768;
        const float* Wql  = Wq  + l * 16384;
        const float* bql  = bq  + l * 128;
        const float* Wkvl = Wkv + l * 65536;
        const float* bkvl = bkv + l * 256;
        const float* Wol  = Wo  + l * 16384;
        const float* bol  = bo  + l * 128;
        const float* xin  = (l == 0) ? tok : bufA;
        float* outs       = (l == 0) ? bufA : bufB;
        const int Mkv     = (l == 0) ? BS_TOT : 8 * BS_TOT;
        const int nt      = (l == 0) ? 1 : 8;

        prep_k<<<dim3(1024), dim3(256), 0, stream>>>(hbuf, svb, ovb, W1T, WoT, CT,
                                                     Al, Wql, Wol, Cl, cnts);

        gemm_k<64, 64, 16, 4, 4><<<dim3(256 / 64, Mkv / 64), dim3(256), 0, stream>>>(
            xin, Wkvl, bkvl, kvb, Mkv, 256, 256);

        ktrans_k<<<dim3(16, nt), dim3(256), 0, stream>>>(kvb, kTb);

        for (int t = 0; t <= TSTEPS; ++t) {
            const int do_B = (t < TSTEPS) ? 1 : 0;
            float* outs_prev = outs + (size_t)((t > 0) ? (t - 1) : 0) * NE;
            lif_k<<<dim3(256), dim3(256), 0, stream>>>(
                W1T, WoT, CT, bql, bol,
                hbuf, svb, ovb, attb, outs_prev, qg,
                cnts, cnts + 8, t, do_B);
            if (do_B) {
                const float* kT_t = (l == 0) ? kTb : kTb + (size_t)t * 131072;
                const float* kv_t = (l == 0) ? kvb : kvb + (size_t)t * NE;
                attn_k<<<dim3(512), dim3(256), 0, stream>>>(qg, kT_t, kv_t, attb);
            }
        }
    }

    mean_k<<<dim3(1024), dim3(256), 0, stream>>>(bufB, ti);

    // logits = ti @ Wout^T + bout : 128x128x32 global_load_lds + swizzle
    gemm_out_k<<<dim3(2000), dim3(256), 0, stream>>>(ti, Wout, bout, out);
}

// Round 8
// 1236.565 us; speedup vs baseline: 1.0470x; 1.0470x over previous
//
#include <hip/hip_runtime.h>
#include <math.h>

// ---- model constants ----
#define BS_TOT   1024          // B*S
#define DM       256           // d_model
#define DST      128           // d_state
#define TSTEPS   8
#define DECAYF   0.6065306597126334f
#define SCALEF   0.17677669529663689f   // 1/sqrt(32)
#define NE       (BS_TOT * DM)          // 262144

// ======================= embedding =======================
__global__ void embed_k(const int* __restrict__ ids, const float* __restrict__ emb,
                        float* __restrict__ tok) {
    int r = blockIdx.x, c = threadIdx.x;
    tok[r * DM + c] = emb[(size_t)ids[r] * DM + c];
}

// ======================= per-layer prep: zero state + transpose weights ==========
// grid 1024 x 256 (262144 threads)
__global__ void prep_k(float* __restrict__ h, float* __restrict__ sv, float* __restrict__ ov,
                       float* __restrict__ W1T, float* __restrict__ WoT, float* __restrict__ CT,
                       const float* __restrict__ Al, const float* __restrict__ Wql,
                       const float* __restrict__ Wol, const float* __restrict__ Cl,
                       int* __restrict__ cnts) {
    int i = blockIdx.x * 256 + threadIdx.x;
    if (i < BS_TOT * DST) { h[i] = 0.f; sv[i] = 0.f; }
    ov[i] = 0.f;
    if (i < 32768) {
        int k = i >> 8, n = i & 255;
        W1T[i] = (n < 128) ? Al[n * 128 + k] : Wql[(n - 128) * 128 + k];
        CT[i]  = Cl[n * 128 + k];
    }
    if (i < 16384) {
        int k = i >> 7, n = i & 127;
        WoT[i] = Wol[n * 128 + k];
    }
    if (i < 16) cnts[i] = 0;
}

// ======================= k-half transpose: kv[key][0..127] -> kT[d][key] =========
__global__ __launch_bounds__(256) void ktrans_k(const float* __restrict__ kv,
                                                float* __restrict__ kT) {
    __shared__ float tile[64][133];
    const float* src = kv + (size_t)blockIdx.y * NE;
    float* dst = kT + (size_t)blockIdx.y * (128 * 1024);
    const int kc = blockIdx.x, tid = threadIdx.x;
#pragma unroll
    for (int i = 0; i < 32; ++i) {
        int idx = i * 256 + tid;
        int key = idx >> 7, d = idx & 127;
        tile[key][d] = src[(size_t)(kc * 64 + key) * 256 + d];
    }
    __syncthreads();
#pragma unroll
    for (int i = 0; i < 32; ++i) {
        int idx = i * 256 + tid;
        int d = idx >> 6, key = idx & 63;
        dst[(size_t)d * 1024 + kc * 64 + key] = tile[key][d];
    }
}

// ======================= time-mean =======================
__global__ void mean_k(const float* __restrict__ outs, float* __restrict__ ti) {
    int i = blockIdx.x * 256 + threadIdx.x;
    float s = 0.f;
#pragma unroll
    for (int t = 0; t < TSTEPS; ++t) s += outs[t * NE + i];
    ti[i] = s * 0.125f;
}

// ======================= generic fp32 GEMM (plain, +bias) =======================
template <int BM, int BN, int BK, int TM, int TN>
__global__ __launch_bounds__((BM / TM) * (BN / TN))
void gemm_k(const float* __restrict__ Amat, const float* __restrict__ Wmat,
            const float* __restrict__ bias, float* __restrict__ outp,
            int M, int N, int K) {
    constexpr int NT  = (BM / TM) * (BN / TN);
    constexpr int NXT = BN / TN;
    __shared__ float As[BK][BM + 4];
    __shared__ float Bs[BK][BN + 4];
    const int tid = threadIdx.x;
    const int n0 = blockIdx.x * BN, m0 = blockIdx.y * BM;
    const int tx = tid % NXT, ty = tid / NXT;
    float acc[TM][TN] = {};

    for (int k0 = 0; k0 < K; k0 += BK) {
#pragma unroll
        for (int i = 0; i < (BM * BK) / NT; ++i) {
            int idx = i * NT + tid;
            int kk = idx % BK, mm = idx / BK;
            As[kk][mm] = Amat[(size_t)(m0 + mm) * K + k0 + kk];
        }
#pragma unroll
        for (int i = 0; i < (BN * BK) / NT; ++i) {
            int idx = i * NT + tid;
            int kk = idx % BK, nn = idx / BK;
            Bs[kk][nn] = Wmat[(size_t)(n0 + nn) * K + k0 + kk];
        }
        __syncthreads();
#pragma unroll
        for (int kk = 0; kk < BK; ++kk) {
            float a[TM], b[TN];
#pragma unroll
            for (int i = 0; i < TM; ++i) a[i] = As[kk][ty * TM + i];
#pragma unroll
            for (int j = 0; j < TN; ++j) b[j] = Bs[kk][tx * TN + j];
#pragma unroll
            for (int i = 0; i < TM; ++i)
#pragma unroll
                for (int j = 0; j < TN; ++j) acc[i][j] += a[i] * b[j];
        }
        __syncthreads();
    }
#pragma unroll
    for (int i = 0; i < TM; ++i) {
        int mr = m0 + ty * TM + i;
#pragma unroll
        for (int j = 0; j < TN; ++j) {
            int nc = n0 + tx * TN + j;
            float x = acc[i][j];
            if (bias) x += bias[nc];
            outp[(size_t)mr * N + nc] = x;
        }
    }
}

// ======================= logits GEMM: 128x128x32, split 4+4 tiles ================
// EXACT round-5 version (measured 201.5 us, VGPR 76, occ 28.7%): 2000 blocks x
// 256 thr, XCD-swizzled, BK=32, float4 global staging, reg-staged ds_writes,
// conflict-free split-tile float4 fragment reads. Round-6's global_load_lds
// variant regressed (VGPR 104, occ 20.8, 240 us) - do not reapply.
// Per-output k-chain ascending (k0 asc by 32, kk asc 0..31) -> bit-identical.
__global__ __launch_bounds__(256) void gemm_out_k(
    const float* __restrict__ Amat, const float* __restrict__ Wmat,
    const float* __restrict__ bias, float* __restrict__ outp)
{
    constexpr int BM = 128, BN = 128, BK = 32;
    constexpr int K = 256, N = 32000;
    __shared__ float As[BK][BM + 4];   // 16.9 KB
    __shared__ float Bs[BK][BN + 4];   // 16.9 KB  -> 33.8 KB total, 4 blocks/CU
    const int tid = threadIdx.x;

    // bijective XCD swizzle: 2000 blocks, 2000 % 8 == 0
    const int bid = blockIdx.x;
    const int g   = (bid & 7) * 250 + (bid >> 3);
    const int m0  = (g & 7) * BM;          // row-block fastest within an XCD chunk
    const int n0  = (g >> 3) * BN;         // column panel

    const int tx = tid & 15, ty = tid >> 4;
    // acc[i][j]: row = m0 + (i<4 ? ty*4+i : 64+ty*4+i-4)
    //            col = n0 + (j<4 ? tx*4+j : 64+tx*4+j-4)
    float acc[8][8] = {};

    for (int k0 = 0; k0 < K; k0 += BK) {
        // stage: 128 rows x 8 float4-slots each for A and B; 4 slots per thread.
        // lane->(mm, k4): k4 fastest => 8 lanes read one row's 128B contiguously.
#pragma unroll
        for (int i = 0; i < 4; ++i) {
            int idx = i * 256 + tid;           // 0..1023
            int mm = idx >> 3, k4 = idx & 7;
            float4 va = *(const float4*)&Amat[(size_t)(m0 + mm) * K + k0 + k4 * 4];
            As[k4 * 4 + 0][mm] = va.x; As[k4 * 4 + 1][mm] = va.y;
            As[k4 * 4 + 2][mm] = va.z; As[k4 * 4 + 3][mm] = va.w;
            float4 vb = *(const float4*)&Wmat[(size_t)(n0 + mm) * K + k0 + k4 * 4];
            Bs[k4 * 4 + 0][mm] = vb.x; Bs[k4 * 4 + 1][mm] = vb.y;
            Bs[k4 * 4 + 2][mm] = vb.z; Bs[k4 * 4 + 3][mm] = vb.w;
        }
        __syncthreads();
#pragma unroll
        for (int kk = 0; kk < BK; ++kk) {
            float a[8], b[8];
            *(float4*)&a[0] = *(const float4*)&As[kk][ty * 4];
            *(float4*)&a[4] = *(const float4*)&As[kk][64 + ty * 4];
            *(float4*)&b[0] = *(const float4*)&Bs[kk][tx * 4];
            *(float4*)&b[4] = *(const float4*)&Bs[kk][64 + tx * 4];
#pragma unroll
            for (int i = 0; i < 8; ++i)
#pragma unroll
                for (int j = 0; j < 8; ++j) acc[i][j] += a[i] * b[j];
        }
        __syncthreads();
    }

    float bv[8];
    *(float4*)&bv[0] = *(const float4*)&bias[n0 + tx * 4];
    *(float4*)&bv[4] = *(const float4*)&bias[n0 + 64 + tx * 4];
#pragma unroll
    for (int i = 0; i < 8; ++i) {
        const int mr = m0 + ((i < 4) ? (ty * 4 + i) : (64 + ty * 4 + i - 4));
        float4 o0, o1;
        o0.x = acc[i][0] + bv[0]; o0.y = acc[i][1] + bv[1];
        o0.z = acc[i][2] + bv[2]; o0.w = acc[i][3] + bv[3];
        o1.x = acc[i][4] + bv[4]; o1.y = acc[i][5] + bv[5];
        o1.z = acc[i][6] + bv[6]; o1.w = acc[i][7] + bv[7];
        float* dst = &outp[(size_t)mr * N + n0];
        *(float4*)(dst + tx * 4)      = o0;
        *(float4*)(dst + 64 + tx * 4) = o1;
    }
}

// ======================= L-kernel: LIF of step t-1 + q of step t ==================
// EXACT round-0 version (separate A2/B1 walks). The fused/prefetch variant
// measured ~+15 us aggregate across rounds - do not reapply.
__global__ __launch_bounds__(256) void lif_k(
    const float* __restrict__ W1T,        // [128][256]  ([A|Wq] transposed)
    const float* __restrict__ WoT,        // [128][128]
    const float* __restrict__ CT,         // [128][256]
    const float* __restrict__ bq_w,       // [128]
    const float* __restrict__ bo_w,       // [128]
    float* __restrict__ h,                // [1024][128] spikes (in/out, in-place)
    float* __restrict__ sv,               // [1024][128]
    float* __restrict__ ov,               // [1024][256]
    const float* __restrict__ att_in,     // [1024][128]  att(t-1)
    float* __restrict__ outs_prev,        // outs[t-1]
    float* __restrict__ q_g,              // [1024][128]
    int* __restrict__ cnt1, int* __restrict__ cnt2, int t, int do_B)
{
    __shared__ float hA_s[4 * 128];
    __shared__ float h2_s[4 * 128];
    __shared__ float att_s[4 * 128];
    __shared__ unsigned long long umr_s[4][2];
    __shared__ unsigned long long um_s[2];
    __shared__ float thr_s[2];

    const int tid = threadIdx.x;
    const int r0 = blockIdx.x * 4;

    if (tid == 0) {
        float ts = 1.0f, to = 1.0f;
        for (int i = 0; i < t - 1; ++i) {
            float e1 = (float)cnt1[i] * (1.f / 131072.f) - 0.02f;
            ts = fmaxf(ts + 0.1f * e1, 0.5f);
            float e2 = (float)cnt2[i] * (1.f / 262144.f) - 0.02f;
            to = fmaxf(to + 0.1f * e2, 0.5f);
        }
        thr_s[0] = ts; thr_s[1] = to;
    }
    hA_s[tid]       = h[r0 * 128 + tid];
    hA_s[256 + tid] = h[r0 * 128 + 256 + tid];
    if (t > 0) {
        att_s[tid]       = att_in[r0 * 128 + tid];
        att_s[256 + tid] = att_in[r0 * 128 + 256 + tid];
    }
    __syncthreads();
    {   // per-row ballots of h_old (wave w -> row w)
        int w = tid >> 6, l = tid & 63;
        unsigned long long b0 = __ballot(hA_s[w * 128 + l] != 0.f);
        unsigned long long b1 = __ballot(hA_s[w * 128 + 64 + l] != 0.f);
        if (l == 0) { umr_s[w][0] = b0; umr_s[w][1] = b1; }
    }
    __syncthreads();
    if (tid == 0) {
        um_s[0] = umr_s[0][0] | umr_s[1][0] | umr_s[2][0] | umr_s[3][0];
        um_s[1] = umr_s[0][1] | umr_s[1][1] | umr_s[2][1] | umr_s[3][1];
    }
    __syncthreads();

    const int n = tid & 127, half = tid >> 7;   // rows 2*half, 2*half+1
    const int ra = half * 2, rb = half * 2 + 1;

    if (t > 0) {
        // ---- A1: st = h_old@A^T (sparse), b = att@Wo^T (dense); LIF1 -> h2 ----
        float sta = 0.f, stb = 0.f;
        unsigned long long u = um_s[0];
        while (u) {
            int k = __builtin_ctzll(u); u &= u - 1;
            float w = W1T[(k << 8) + n];
            sta += hA_s[ra * 128 + k] * w; stb += hA_s[rb * 128 + k] * w;
        }
        u = um_s[1];
        while (u) {
            int kk = __builtin_ctzll(u); u &= u - 1;
            int k = 64 + kk;
            float w = W1T[(k << 8) + n];
            sta += hA_s[ra * 128 + k] * w; stb += hA_s[rb * 128 + k] * w;
        }
        float ba = 0.f, bb = 0.f;
        for (int i4 = 0; i4 < 32; ++i4) {
            const int i = i4 * 4;
            float w0 = WoT[(i + 0) * 128 + n];
            float w1 = WoT[(i + 1) * 128 + n];
            float w2 = WoT[(i + 2) * 128 + n];
            float w3 = WoT[(i + 3) * 128 + n];
            float4 aa = *(const float4*)&att_s[ra * 128 + i];
            float4 ab = *(const float4*)&att_s[rb * 128 + i];
            ba += aa.x * w0; ba += aa.y * w1; ba += aa.z * w2; ba += aa.w * w3;
            bb += ab.x * w0; bb += ab.y * w1; bb += ab.z * w2; bb += ab.w * w3;
        }
        float ts = thr_s[0];
        float xa = ba + bo_w[n]; xa += sta;
        float va = sv[(r0 + ra) * 128 + n];
        float vpa = va * DECAYF + xa;
        float spa = (vpa - ts >= 0.f) ? 1.f : 0.f;
        h[(r0 + ra) * 128 + n]  = spa;
        sv[(r0 + ra) * 128 + n] = vpa * (1.f - spa);
        h2_s[ra * 128 + n] = spa;

        float xb = bb + bo_w[n]; xb += stb;
        float vb = sv[(r0 + rb) * 128 + n];
        float vpb = vb * DECAYF + xb;
        float spb = (vpb - ts >= 0.f) ? 1.f : 0.f;
        h[(r0 + rb) * 128 + n]  = spb;
        sv[(r0 + rb) * 128 + n] = vpb * (1.f - spb);
        h2_s[rb * 128 + n] = spb;

        unsigned long long bba = __ballot(spa != 0.f);
        unsigned long long bbb = __ballot(spb != 0.f);
        int w = tid >> 6, l = tid & 63;
        if (l == 0) {
            umr_s[ra][w & 1] = bba;
            umr_s[rb][w & 1] = bbb;
            atomicAdd(&cnt1[t - 1], __popcll(bba) + __popcll(bbb));
        }
    } else {
        h2_s[tid]       = hA_s[tid];          // zeros
        h2_s[256 + tid] = hA_s[256 + tid];
        // umr stays = zero ballots of h
    }
    __syncthreads();
    if (tid == 0) {
        um_s[0] = umr_s[0][0] | umr_s[1][0] | umr_s[2][0] | umr_s[3][0];
        um_s[1] = umr_s[0][1] | umr_s[1][1] | umr_s[2][1] | umr_s[3][1];
    }
    __syncthreads();

    if (t > 0) {
        // ---- A2: out_pot = h2@C^T (sparse) -> LIF2 -> outs[t-1] ----
        const int n2 = tid;
        float a0 = 0.f, a1 = 0.f, a2 = 0.f, a3 = 0.f;
        unsigned long long u = um_s[0];
        while (u) {
            int k = __builtin_ctzll(u); u &= u - 1;
            float w = CT[(k << 8) + n2];
            a0 += h2_s[k] * w;       a1 += h2_s[128 + k] * w;
            a2 += h2_s[256 + k] * w; a3 += h2_s[384 + k] * w;
        }
        u = um_s[1];
        while (u) {
            int kk = __builtin_ctzll(u); u &= u - 1;
            int k = 64 + kk;
            float w = CT[(k << 8) + n2];
            a0 += h2_s[k] * w;       a1 += h2_s[128 + k] * w;
            a2 += h2_s[256 + k] * w; a3 += h2_s[384 + k] * w;
        }
        float to = thr_s[1];
        float accs[4] = {a0, a1, a2, a3};
        float sp[4];
#pragma unroll
        for (int r = 0; r < 4; ++r) {
            float vo = ov[(r0 + r) * 256 + n2];
            float vp = vo * DECAYF + accs[r];
            float s = (vp - to >= 0.f) ? 1.f : 0.f;
            sp[r] = s;
            outs_prev[(size_t)(r0 + r) * 256 + n2] = s;
            ov[(r0 + r) * 256 + n2] = vp * (1.f - s);
        }
        unsigned long long c0 = __ballot(sp[0] != 0.f);
        unsigned long long c1 = __ballot(sp[1] != 0.f);
        unsigned long long c2 = __ballot(sp[2] != 0.f);
        unsigned long long c3 = __ballot(sp[3] != 0.f);
        if ((tid & 63) == 0)
            atomicAdd(&cnt2[t - 1], __popcll(c0) + __popcll(c1) + __popcll(c2) + __popcll(c3));
    }

    if (do_B) {
        // ---- B1: q = h2@Wq^T + bq (sparse), cols 128..255 of W1T ----
        float qa = 0.f, qb = 0.f;
        unsigned long long u = um_s[0];
        while (u) {
            int k = __builtin_ctzll(u); u &= u - 1;
            float w = W1T[(k << 8) + 128 + n];
            qa += h2_s[ra * 128 + k] * w; qb += h2_s[rb * 128 + k] * w;
        }
        u = um_s[1];
        while (u) {
            int kk = __builtin_ctzll(u); u &= u - 1;
            int k = 64 + kk;
            float w = W1T[(k << 8) + 128 + n];
            qa += h2_s[ra * 128 + k] * w; qb += h2_s[rb * 128 + k] * w;
        }
        q_g[(r0 + ra) * 128 + n] = qa + bq_w[n];
        q_g[(r0 + rb) * 128 + n] = qb + bq_w[n];
    }
}

// ======================= S-kernel: scores/softmax/PV for one head =================
// grid = 128 row-tiles x 4 heads = 512 blocks, 256 threads, 8 rows per block.
// Round-0 structure (44.4 KB LDS -> 3 blocks/CU; 2-wave PV with 2 barriers/iter)
// with ONE change: B2's acc stays in registers across both d-passes instead of
// round-tripping through p_s between passes. Same FMA chain (d ascending),
// SCALEF applied after the full sum as before -> bit-exact; saves 16 wave-wide
// b128 LDS ops per block.
__global__ __launch_bounds__(256) void attn_k(
    const float* __restrict__ q_g,        // [1024][128]
    const float* __restrict__ kT,         // [128][1024]
    const float* __restrict__ kv,         // [1024][256] (v half used)
    float* __restrict__ att_out)          // [1024][128]
{
    __shared__ float p_s[8][1032];
    __shared__ float v_s[64 * 36];
    __shared__ float q_s[8][32];
    __shared__ float red_s[8 * 33];
    __shared__ float mrow_s[8], linv_s[8];

    const int tid = threadIdx.x;
    const int hh = blockIdx.x >> 7;
    const int r0 = (blockIdx.x & 127) * 8;

    {   // stage q (8 rows x 32 dims)
        int r = tid >> 5, d = tid & 31;
        q_s[r][d] = q_g[(size_t)(r0 + r) * 128 + hh * 32 + d];
    }
    __syncthreads();

    // ---- B2: scores. Lane owns 4 keys; acc lives in regs across both d-passes.
    {
        const int w = tid >> 6, l = tid & 63;
        const int key4 = w * 64 + l;                 // float4 index into 1024 keys
        const float4* kT4 = (const float4*)(kT + (size_t)hh * 32 * 1024);
        float4 acc[8];
#pragma unroll
        for (int r = 0; r < 8; ++r) acc[r] = make_float4(0.f, 0.f, 0.f, 0.f);
#pragma unroll
        for (int pass = 0; pass < 2; ++pass) {
            const int d0 = pass * 16;
            float4 kreg[16];
#pragma unroll
            for (int i = 0; i < 16; ++i) kreg[i] = kT4[(size_t)(d0 + i) * 256 + key4];
#pragma unroll
            for (int i4 = 0; i4 < 4; ++i4) {
#pragma unroll
                for (int r = 0; r < 8; ++r) {
                    float4 qv = *(const float4*)&q_s[r][d0 + i4 * 4];
                    float4 k0 = kreg[i4 * 4 + 0], k1 = kreg[i4 * 4 + 1];
                    float4 k2 = kreg[i4 * 4 + 2], k3 = kreg[i4 * 4 + 3];
                    acc[r].x += qv.x * k0.x; acc[r].x += qv.y * k1.x;
                    acc[r].x += qv.z * k2.x; acc[r].x += qv.w * k3.x;
                    acc[r].y += qv.x * k0.y; acc[r].y += qv.y * k1.y;
                    acc[r].y += qv.z * k2.y; acc[r].y += qv.w * k3.y;
                    acc[r].z += qv.x * k0.z; acc[r].z += qv.y * k1.z;
                    acc[r].z += qv.z * k2.z; acc[r].z += qv.w * k3.z;
                    acc[r].w += qv.x * k0.w; acc[r].w += qv.y * k1.w;
                    acc[r].w += qv.z * k2.w; acc[r].w += qv.w * k3.w;
                }
            }
        }
#pragma unroll
        for (int r = 0; r < 8; ++r) {
            acc[r].x *= SCALEF; acc[r].y *= SCALEF;
            acc[r].z *= SCALEF; acc[r].w *= SCALEF;
            *(float4*)&p_s[r][key4 * 4] = acc[r];
        }
    }
    __syncthreads();

    // ---- B3: softmax (identical per-row reduction order to earlier rounds) ----
    {
        const int rh = tid >> 5, lg = tid & 31;
        float mx = -1e30f;
        for (int jj = 0; jj < 32; ++jj) mx = fmaxf(mx, p_s[rh][lg + 32 * jj]);
        red_s[rh * 33 + lg] = mx;
        __syncthreads();
        if (tid < 8) {
            float m = red_s[tid * 33];
            for (int j = 1; j < 32; ++j) m = fmaxf(m, red_s[tid * 33 + j]);
            mrow_s[tid] = m;
        }
        __syncthreads();
        float m = mrow_s[rh];
        float ls = 0.f;
        for (int jj = 0; jj < 32; ++jj) {
            int a = lg + 32 * jj;
            float p = expf(p_s[rh][a] - m);
            p_s[rh][a] = p;
            ls += p;
        }
        red_s[rh * 33 + lg] = ls;
        __syncthreads();
        if (tid < 8) {
            float l = 0.f;
            for (int j = 0; j < 32; ++j) l += red_s[tid * 33 + j];
            linv_s[tid] = 1.0f / l;
        }
    }
    __syncthreads();

    // ---- B4: PV. Waves 0,1 compute (4 rows x 16 dim-pairs each); all stage. ----
    {
        const int w = tid >> 6, l = tid & 63;
        const int r = (w & 1) * 4 + (l >> 4);
        const int dp = l & 15;
        const bool act = (w < 2);
        const float4* kv4 = (const float4*)kv;
        float4 stg0, stg1;
        {
            int i0 = tid, i1 = 256 + tid;
            stg0 = kv4[(size_t)(i0 >> 3) * 64 + 32 + hh * 8 + (i0 & 7)];
            stg1 = kv4[(size_t)(i1 >> 3) * 64 + 32 + hh * 8 + (i1 & 7)];
        }
        float a0 = 0.f, a1 = 0.f;
        for (int c = 0; c < 16; ++c) {
            {
                int i0 = tid, i1 = 256 + tid;
                *(float4*)&v_s[(i0 >> 3) * 36 + (i0 & 7) * 4] = stg0;
                *(float4*)&v_s[(i1 >> 3) * 36 + (i1 & 7) * 4] = stg1;
            }
            if (c < 15) {
                int i0 = tid, i1 = 256 + tid;
                stg0 = kv4[(size_t)((c + 1) * 64 + (i0 >> 3)) * 64 + 32 + hh * 8 + (i0 & 7)];
                stg1 = kv4[(size_t)((c + 1) * 64 + (i1 >> 3)) * 64 + 32 + hh * 8 + (i1 & 7)];
            }
            __syncthreads();
            if (act) {
#pragma unroll 4
                for (int k4 = 0; k4 < 16; ++k4) {
                    const int kb = k4 * 4;
                    float4 p4 = *(const float4*)&p_s[r][c * 64 + kb];
                    float2 v0 = *(const float2*)&v_s[(kb + 0) * 36 + 2 * dp];
                    float2 v1 = *(const float2*)&v_s[(kb + 1) * 36 + 2 * dp];
                    float2 v2 = *(const float2*)&v_s[(kb + 2) * 36 + 2 * dp];
                    float2 v3 = *(const float2*)&v_s[(kb + 3) * 36 + 2 * dp];
                    a0 += p4.x * v0.x; a1 += p4.x * v0.y;
                    a0 += p4.y * v1.x; a1 += p4.y * v1.y;
                    a0 += p4.z * v2.x; a1 += p4.z * v2.y;
                    a0 += p4.w * v3.x; a1 += p4.w * v3.y;
                }
            }
            __syncthreads();
        }
        if (act) {
            float li = linv_s[r];
            *(float2*)&att_out[(size_t)(r0 + r) * 128 + hh * 32 + 2 * dp] =
                make_float2(a0 * li, a1 * li);
        }
    }
}

// ======================= host =======================
extern "C" void kernel_launch(void* const* d_in, const int* in_sizes, int n_in,
                              void* d_out, int out_size, void* d_ws, size_t ws_size,
                              hipStream_t stream) {
    (void)in_sizes; (void)n_in; (void)out_size; (void)ws_size;
    const int*   ids  = (const int*)d_in[0];
    const float* emb  = (const float*)d_in[1];
    const float* Aw   = (const float*)d_in[2];
    const float* Cw   = (const float*)d_in[3];
    const float* Wq   = (const float*)d_in[4];
    const float* bq   = (const float*)d_in[5];
    const float* Wkv  = (const float*)d_in[6];
    const float* bkv  = (const float*)d_in[7];
    const float* Wo   = (const float*)d_in[8];
    const float* bo   = (const float*)d_in[9];
    const float* Wout = (const float*)d_in[10];
    const float* bout = (const float*)d_in[11];
    float* out = (float*)d_out;
    float* ws  = (float*)d_ws;

    float* tok  = ws;                       // 262144
    float* bufA = tok  + NE;                // 8*262144
    float* bufB = bufA + 8 * NE;            // 8*262144
    float* kvb  = bufB + 8 * NE;            // 8*262144
    float* kTb  = kvb  + 8 * NE;            // 8*131072
    float* attb = kTb  + 8 * 131072;        // 131072
    float* hbuf = attb + 131072;            // 131072
    float* svb  = hbuf + 131072;            // 131072
    float* ovb  = svb  + 131072;            // 262144
    float* qg   = ovb  + 262144;            // 131072
    float* ti   = qg   + 131072;            // 262144
    float* W1T  = ti   + NE;                // 32768
    float* WoT  = W1T  + 32768;             // 16384
    float* CT   = WoT  + 16384;             // 32768
    int*   cnts = (int*)(CT + 32768);       // cnt1[8], cnt2[8]

    embed_k<<<dim3(1024), dim3(256), 0, stream>>>(ids, emb, tok);

    for (int l = 0; l < 2; ++l) {
        const float* Al   = Aw  + l * 16384;
        const float* Cl   = Cw  + l * 32768;
        const float* Wql  = Wq  + l * 16384;
        const float* bql  = bq  + l * 128;
        const float* Wkvl = Wkv + l * 65536;
        const float* bkvl = bkv + l * 256;
        const float* Wol  = Wo  + l * 16384;
        const float* bol  = bo  + l * 128;
        const float* xin  = (l == 0) ? tok : bufA;
        float* outs       = (l == 0) ? bufA : bufB;
        const int Mkv     = (l == 0) ? BS_TOT : 8 * BS_TOT;
        const int nt      = (l == 0) ? 1 : 8;

        prep_k<<<dim3(1024), dim3(256), 0, stream>>>(hbuf, svb, ovb, W1T, WoT, CT,
                                                     Al, Wql, Wol, Cl, cnts);

        gemm_k<64, 64, 16, 4, 4><<<dim3(256 / 64, Mkv / 64), dim3(256), 0, stream>>>(
            xin, Wkvl, bkvl, kvb, Mkv, 256, 256);

        ktrans_k<<<dim3(16, nt), dim3(256), 0, stream>>>(kvb, kTb);

        for (int t = 0; t <= TSTEPS; ++t) {
            const int do_B = (t < TSTEPS) ? 1 : 0;
            float* outs_prev = outs + (size_t)((t > 0) ? (t - 1) : 0) * NE;
            lif_k<<<dim3(256), dim3(256), 0, stream>>>(
                W1T, WoT, CT, bql, bol,
                hbuf, svb, ovb, attb, outs_prev, qg,
                cnts, cnts + 8, t, do_B);
            if (do_B) {
                const float* kT_t = (l == 0) ? kTb : kTb + (size_t)t * 131072;
                const float* kv_t = (l == 0) ? kvb : kvb + (size_t)t * NE;
                attn_k<<<dim3(512), dim3(256), 0, stream>>>(qg, kT_t, kv_t, attb);
            }
        }
    }

    mean_k<<<dim3(1024), dim3(256), 0, stream>>>(bufB, ti);

    // logits = ti @ Wout^T + bout : 128x128x32 split-tile, XCD-swizzled (R5 best)
    gemm_out_k<<<dim3(2000), dim3(256), 0, stream>>>(ti, Wout, bout, out);
}